// Round 1
// baseline (4914.537 us; speedup 1.0000x reference)
//
#include <hip/hip_runtime.h>

typedef _Float16 f16x2 __attribute__((ext_vector_type(2)));

__device__ __forceinline__ float eluf(float x)   { return x > 0.f ? x : expm1f(x); }
__device__ __forceinline__ float sigmf_(float x) { return 1.f / (1.f + __expf(-x)); }

// ---------------- done dtype normalize (bool pushed as u8 / i32 / f32 ?) ----
__global__ void k_done(const unsigned char* __restrict__ raw,
                       unsigned char* __restrict__ out) {
  __shared__ int flagNon0;  // any nonzero byte at i%4 != 0
  __shared__ int flagAt0;   // any nonzero byte at i%4 == 0
  if (threadIdx.x == 0) { flagNon0 = 0; flagAt0 = 0; }
  __syncthreads();
  int l0 = 0, l1 = 0;
  for (int i = threadIdx.x; i < 16384; i += 256) {   // only first 16KB: safe for all dtypes
    if (raw[i]) { if (i & 3) l0 = 1; else l1 = 1; }
  }
  if (l0) atomicOr(&flagNon0, 1);
  if (l1) atomicOr(&flagAt0, 1);
  __syncthreads();
  // u8: ones everywhere; i32(0/1): bytes only at i%4==0; f32(1.0f=00 00 80 3F): only i%4 in {2,3}
  int mode = (flagNon0 && flagAt0) ? 0 : (flagAt0 ? 1 : (flagNon0 ? 2 : 0));
  for (int i = threadIdx.x; i < 16384; i += 256) {
    unsigned char v;
    if (mode == 0)      v = raw[i] ? 1 : 0;
    else if (mode == 1) v = ((const int*)raw)[i] ? 1 : 0;
    else                v = (((const float*)raw)[i] != 0.f) ? 1 : 0;
    out[i] = v;
  }
}

// ---------------- conv stack + readin + xgates ------------------------------
// one wave per sample; 4 waves (256 thr) per block
__global__ __launch_bounds__(256) void k_conv(
    const float* __restrict__ inp,
    const float* __restrict__ c1w, const float* __restrict__ c1b,
    const float* __restrict__ c2w, const float* __restrict__ c2b,
    const float* __restrict__ c3w, const float* __restrict__ c3b,
    const float* __restrict__ riw, const float* __restrict__ rib,
    const float* __restrict__ wih, const float* __restrict__ bih,
    const float* __restrict__ bhh,
    float* __restrict__ xg)   // layout [tx][512][64]
{
  __shared__ float sm[4][243 + 1152 + 128 + 128 + 128];  // per-wave scratch
  const int lane = threadIdx.x & 63;
  const int wv   = threadIdx.x >> 6;
  const int n    = blockIdx.x * 4 + wv;      // sample index in [0,16384)
  float* S   = sm[wv];
  float* img = S;             // [3][9][9]  zero-padded (+1 border)
  float* a1  = S + 243;       // [32][6][6] zero-padded (+1 border)
  float* a2  = a1 + 1152;     // [32][2][2]
  float* ft  = a2 + 128;      // [128]
  float* y   = ft + 128;      // [128]

  for (int i = lane; i < 243 + 1152; i += 64) S[i] = 0.f;
  __syncthreads();

  // x = transpose(inputs,(0,3,2,1)): img[c][p=w][q=h] = inp[n][h=q][w=p][c]
  const float* src = inp + n * 147;
  for (int i = lane; i < 147; i += 64) {
    int c = i % 3, p = (i / 3) % 7, q = i / 21;
    img[(c * 9 + (p + 1)) * 9 + (q + 1)] = src[q * 21 + p * 3 + c];
  }
  __syncthreads();

  // conv1: 3->32, 7x7 -> 4x4, stride2 pad1 (padded idx: 2p+dp)
  for (int r = 0; r < 8; ++r) {
    int idx = r * 64 + lane;                 // 512 outputs
    int o = idx >> 4, s = idx & 15, p = s >> 2, q = s & 3;
    float acc = c1b[o];
    const float* wr = c1w + o * 27;
    #pragma unroll
    for (int i = 0; i < 3; ++i)
      #pragma unroll
      for (int dp = 0; dp < 3; ++dp)
        #pragma unroll
        for (int dq = 0; dq < 3; ++dq)
          acc += img[(i * 9 + (2 * p + dp)) * 9 + (2 * q + dq)] * wr[i * 9 + dp * 3 + dq];
    a1[(o * 6 + (p + 1)) * 6 + (q + 1)] = eluf(acc);
  }
  __syncthreads();

  // conv2: 32->32, 4x4 -> 2x2
  for (int r = 0; r < 2; ++r) {
    int idx = r * 64 + lane;                 // 128 outputs
    int o = idx >> 2, p = (idx >> 1) & 1, q = idx & 1;
    float acc = c2b[o];
    const float* wr = c2w + o * 288;
    for (int i = 0; i < 32; ++i)
      #pragma unroll
      for (int dp = 0; dp < 3; ++dp)
        #pragma unroll
        for (int dq = 0; dq < 3; ++dq)
          acc += a1[(i * 6 + (2 * p + dp)) * 6 + (2 * q + dq)] * wr[i * 9 + dp * 3 + dq];
    a2[idx] = eluf(acc);                     // layout o*4 + p*2 + q
  }
  __syncthreads();

  // conv3: 32->128, 2x2 -> 1x1 (valid taps dp,dq in {1,2})
  for (int r = 0; r < 2; ++r) {
    int o = r * 64 + lane;
    float acc = c3b[o];
    const float* wr = c3w + o * 288;
    for (int i = 0; i < 32; ++i) {
      acc += a2[i * 4 + 0] * wr[i * 9 + 4];
      acc += a2[i * 4 + 1] * wr[i * 9 + 5];
      acc += a2[i * 4 + 2] * wr[i * 9 + 7];
      acc += a2[i * 4 + 3] * wr[i * 9 + 8];
    }
    ft[o] = eluf(acc);
  }
  __syncthreads();

  // readin: y = ft @ riw^T + rib
  for (int r = 0; r < 2; ++r) {
    int jo = r * 64 + lane;
    float acc = rib[jo];
    const float* wr = riw + jo * 128;
    #pragma unroll 8
    for (int k = 0; k < 128; k += 4) {
      float4 w4 = *(const float4*)(wr + k);
      acc = fmaf(y[0] * 0.f + ft[k], w4.x, acc);  // keep simple: ft reads
      acc = fmaf(ft[k + 1], w4.y, acc);
      acc = fmaf(ft[k + 2], w4.z, acc);
      acc = fmaf(ft[k + 3], w4.w, acc);
    }
    y[jo] = acc;
  }
  __syncthreads();

  // xgates = y @ wih^T + bih + bhh, stored transposed [tx][gate][b]
  int t = n >> 6, b = n & 63;
  for (int r = 0; r < 8; ++r) {
    int g = r * 64 + lane;
    float acc = bih[g] + bhh[g];
    const float* wr = wih + g * 128;
    #pragma unroll 8
    for (int k = 0; k < 128; k += 4) {
      float4 w4 = *(const float4*)(wr + k);
      acc = fmaf(y[k], w4.x, acc);
      acc = fmaf(y[k + 1], w4.y, acc);
      acc = fmaf(y[k + 2], w4.z, acc);
      acc = fmaf(y[k + 3], w4.w, acc);
    }
    xg[(t * 512 + g) * 64 + b] = acc;
  }
}

// ---------------- windowed LSTM (16 steps) + readout ------------------------
// block = one (t, b-half): 32 samples; 256 thr = 8 groups x 32; group owns 4
// consecutive b; thread j owns cells {j, j+32, j+64, j+96}.
__global__ __launch_bounds__(256) void k_lstm(
    const float* __restrict__ whh, const float* __restrict__ bih,
    const float* __restrict__ bhh, const float* __restrict__ xg,
    const unsigned char* __restrict__ dun,
    const float* __restrict__ row_, const float* __restrict__ rob,
    float* __restrict__ out)
{
  extern __shared__ char smraw[];
  f16x2*    W2 = (f16x2*)smraw;                    // [512][64] fp16 pairs, 128KB
  f16x2*    H2 = (f16x2*)(smraw + 131072);         // [2][32][64] pairs, 16KB
  _Float16* Hf = (_Float16*)H2;                    // [2][32][128]
  unsigned* HU = (unsigned*)H2;

  const int tid  = threadIdx.x;
  const int t    = blockIdx.x >> 1;
  const int bh   = blockIdx.x & 1;
  const int grp  = tid >> 5;
  const int j    = tid & 31;
  const int bbase = bh * 32 + grp * 4;

  // stage w_hh -> fp16 LDS
  const float2* wsrc = (const float2*)whh;
  for (int i = tid; i < 512 * 64; i += 256) {
    float2 v = wsrc[i];
    f16x2 w; w.x = (_Float16)v.x; w.y = (_Float16)v.y;
    W2[i] = w;
  }
  for (int i = tid; i < 2 * 32 * 64; i += 256) HU[i] = 0u;

  float b0[4][4];   // [a][type]
  #pragma unroll
  for (int a = 0; a < 4; ++a) {
    int jj = j + 32 * a;
    #pragma unroll
    for (int ty = 0; ty < 4; ++ty) b0[a][ty] = bih[ty * 128 + jj] + bhh[ty * 128 + jj];
  }
  float c[4][4];    // [a][sample]
  #pragma unroll
  for (int a = 0; a < 4; ++a)
    #pragma unroll
    for (int si = 0; si < 4; ++si) c[a][si] = 0.f;

  for (int st = 0; st < 16; ++st) {
    int ts = t + st - 15;
    int rb = st & 1, wb = rb ^ 1;
    __syncthreads();                        // staging / prev-step h-writes visible

    if (st > 0 && ts >= 0) {                // done-reset BEFORE this step
      uchar4 dn = *(const uchar4*)&dun[ts * 64 + bbase];
      unsigned char d4[4] = {dn.x, dn.y, dn.z, dn.w};
      #pragma unroll
      for (int si = 0; si < 4; ++si) {
        if (d4[si]) {
          #pragma unroll
          for (int a = 0; a < 4; ++a) c[a][si] = 0.f;
          HU[(rb * 32 + grp * 4 + si) * 64 + j] = 0u;
          HU[(rb * 32 + grp * 4 + si) * 64 + j + 32] = 0u;
        }
      }
      __syncthreads();
    }

    const f16x2* Hr = H2 + (rb * 32 + grp * 4) * 64;
    #pragma unroll
    for (int a = 0; a < 4; ++a) {
      int jj = j + 32 * a;
      float acc[4][4];                      // [type][sample]
      if (ts >= 0) {
        #pragma unroll
        for (int ty = 0; ty < 4; ++ty) {
          float4 xv = *(const float4*)&xg[(ts * 512 + ty * 128 + jj) * 64 + bbase];
          acc[ty][0] = xv.x; acc[ty][1] = xv.y; acc[ty][2] = xv.z; acc[ty][3] = xv.w;
        }
      } else {
        #pragma unroll
        for (int ty = 0; ty < 4; ++ty)
          #pragma unroll
          for (int si = 0; si < 4; ++si) acc[ty][si] = b0[a][ty];
      }
      const f16x2* Wr0 = W2 + (jj)*64;
      const f16x2* Wr1 = W2 + (128 + jj) * 64;
      const f16x2* Wr2 = W2 + (256 + jj) * 64;
      const f16x2* Wr3 = W2 + (384 + jj) * 64;
      #pragma unroll 4
      for (int kp = 0; kp < 64; ++kp) {
        f16x2 wv[4] = {Wr0[kp], Wr1[kp], Wr2[kp], Wr3[kp]};
        f16x2 hv[4] = {Hr[kp], Hr[64 + kp], Hr[128 + kp], Hr[192 + kp]};
        #pragma unroll
        for (int ty = 0; ty < 4; ++ty)
          #pragma unroll
          for (int si = 0; si < 4; ++si) {
            acc[ty][si] = fmaf((float)wv[ty].x, (float)hv[si].x, acc[ty][si]);
            acc[ty][si] = fmaf((float)wv[ty].y, (float)hv[si].y, acc[ty][si]);
          }
      }
      #pragma unroll
      for (int si = 0; si < 4; ++si) {
        float iv = sigmf_(acc[0][si]);
        float fv = sigmf_(acc[1][si]);
        float gv = tanhf(acc[2][si]);
        float ov = sigmf_(acc[3][si]);
        float cn = fmaf(fv, c[a][si], iv * gv);
        c[a][si] = cn;
        float hn = ov * tanhf(cn);
        Hf[(wb * 32 + grp * 4 + si) * 128 + jj] = (_Float16)hn;
      }
    }
  }
  __syncthreads();

  // readout of final h (in buffer 0 after step 15)
  for (int idx = tid; idx < 32 * 128; idx += 256) {
    int s = idx >> 7, e = idx & 127;
    const _Float16* hr = Hf + s * 128;
    float acc = rob[e];
    const float* wr = row_ + e * 128;
    #pragma unroll 8
    for (int k = 0; k < 128; k += 4) {
      float4 w4 = *(const float4*)(wr + k);
      acc = fmaf((float)hr[k],     w4.x, acc);
      acc = fmaf((float)hr[k + 1], w4.y, acc);
      acc = fmaf((float)hr[k + 2], w4.z, acc);
      acc = fmaf((float)hr[k + 3], w4.w, acc);
    }
    out[(t * 64 + bh * 32 + s) * 128 + e] = acc;
  }
}

extern "C" void kernel_launch(void* const* d_in, const int* in_sizes, int n_in,
                              void* d_out, int out_size, void* d_ws, size_t ws_size,
                              hipStream_t stream) {
  const float* inp = (const float*)d_in[0];
  const void*  don = d_in[1];
  const float* c1w = (const float*)d_in[2];
  const float* c1b = (const float*)d_in[3];
  const float* c2w = (const float*)d_in[4];
  const float* c2b = (const float*)d_in[5];
  const float* c3w = (const float*)d_in[6];
  const float* c3b = (const float*)d_in[7];
  const float* riw = (const float*)d_in[8];
  const float* rib = (const float*)d_in[9];
  const float* wih = (const float*)d_in[10];
  const float* whh = (const float*)d_in[11];
  const float* bih = (const float*)d_in[12];
  const float* bhh = (const float*)d_in[13];
  const float* row_ = (const float*)d_in[14];
  const float* rob = (const float*)d_in[15];

  unsigned char* done_u8 = (unsigned char*)d_ws;
  float* xg = (float*)((char*)d_ws + 16384);     // [256][512][64] fp32 = 32MB

  (void)hipFuncSetAttribute((const void*)k_lstm,
                            hipFuncAttributeMaxDynamicSharedMemorySize, 147456);

  k_done<<<1, 256, 0, stream>>>((const unsigned char*)don, done_u8);
  k_conv<<<4096, 256, 0, stream>>>(inp, c1w, c1b, c2w, c2b, c3w, c3b,
                                   riw, rib, wih, bih, bhh, xg);
  k_lstm<<<512, 256, 147456, stream>>>(whh, bih, bhh, xg, done_u8, row_, rob,
                                       (float*)d_out);
}

// Round 3
// 287.564 us; speedup vs baseline: 17.0902x; 17.0902x over previous
//
#include <hip/hip_runtime.h>

typedef _Float16 half8 __attribute__((ext_vector_type(8)));
typedef float f32x4 __attribute__((ext_vector_type(4)));

__device__ __forceinline__ float eluf(float x)   { return x > 0.f ? x : expm1f(x); }
__device__ __forceinline__ float sigf(float x)   { return 1.f / (1.f + __expf(-x)); }
__device__ __forceinline__ float tanhff(float x) { float e = __expf(2.f * x); return 1.f - 2.f / (e + 1.f); }

__device__ __forceinline__ half8 cvt8(const float* __restrict__ p) {
  f32x4 v0 = *(const f32x4*)p;
  f32x4 v1 = *(const f32x4*)(p + 4);
  half8 r;
  r[0] = (_Float16)v0[0]; r[1] = (_Float16)v0[1]; r[2] = (_Float16)v0[2]; r[3] = (_Float16)v0[3];
  r[4] = (_Float16)v1[0]; r[5] = (_Float16)v1[1]; r[6] = (_Float16)v1[2]; r[7] = (_Float16)v1[3];
  return r;
}
__device__ __forceinline__ half8 zero8() {
  half8 z;
  #pragma unroll
  for (int e = 0; e < 8; ++e) z[e] = (_Float16)0.f;
  return z;
}
#define MFMA(a, b, c) __builtin_amdgcn_mfma_f32_16x16x32_f16(a, b, c, 0, 0, 0)

// ---------------- done dtype normalize (bool pushed as u8 / i32 / f32 ?) ----
__global__ void k_done(const unsigned char* __restrict__ raw,
                       unsigned char* __restrict__ out) {
  __shared__ int flagNon0;
  __shared__ int flagAt0;
  if (threadIdx.x == 0) { flagNon0 = 0; flagAt0 = 0; }
  __syncthreads();
  int l0 = 0, l1 = 0;
  for (int i = threadIdx.x; i < 16384; i += 256) {
    if (raw[i]) { if (i & 3) l0 = 1; else l1 = 1; }
  }
  if (l0) atomicOr(&flagNon0, 1);
  if (l1) atomicOr(&flagAt0, 1);
  __syncthreads();
  int mode = (flagNon0 && flagAt0) ? 0 : (flagAt0 ? 1 : (flagNon0 ? 2 : 0));
  for (int i = threadIdx.x; i < 16384; i += 256) {
    unsigned char v;
    if (mode == 0)      v = raw[i] ? 1 : 0;
    else if (mode == 1) v = ((const int*)raw)[i] ? 1 : 0;
    else                v = (((const float*)raw)[i] != 0.f) ? 1 : 0;
    out[i] = v;
  }
}

// ---------------- conv stack + readin + xgates (MFMA) -----------------------
// block = one t (64 samples), 512 threads / 8 waves.
__global__ __launch_bounds__(512, 2) void k_conv(
    const float* __restrict__ inp,
    const float* __restrict__ c1w, const float* __restrict__ c1b,
    const float* __restrict__ c2w, const float* __restrict__ c2b,
    const float* __restrict__ c3w, const float* __restrict__ c3b,
    const float* __restrict__ riw, const float* __restrict__ rib,
    const float* __restrict__ wih, const float* __restrict__ bih,
    const float* __restrict__ bhh,
    float* __restrict__ xg)   // [256 t][512 gate][64 b] f32
{
  extern __shared__ char L[];
  float*    w1t  = (float*)L;                   // [27][32] f32      3456 B
  float*    imgW = (float*)(L + 3456);          // [8][3][9][9] f32  7776 B
  float*    a1W  = (float*)(L + 11232);         // [8][32][6][6] f32 36864 B
  _Float16* ic2  = (_Float16*)(L + 48096);      // [64][320] f16 (padded rows, swizzled) 40960 B
  _Float16* a2   = (_Float16*)(L + 89056);      // [64][128] f16     16384 B (swizzled)
  _Float16* ft   = (_Float16*)(L + 105440);     // [64][128] f16     16384 B (swizzled)
  _Float16* yb   = (_Float16*)(L + 121824);     // [64][128] f16     16384 B (swizzled)

  const int tid  = threadIdx.x;
  const int lane = tid & 63;
  const int wv   = tid >> 6;        // wave 0..7
  const int lr   = lane & 15;
  const int lg   = lane >> 4;
  const int t    = blockIdx.x;

  // stage w1 transposed [k][o]; zero padded scratch (borders stay zero forever)
  for (int i = tid; i < 864; i += 512) w1t[(i % 27) * 32 + (i / 27)] = c1w[i];
  for (int i = tid; i < 8 * 243; i += 512)  imgW[i] = 0.f;
  for (int i = tid; i < 8 * 1152; i += 512) a1W[i] = 0.f;

  // conv2 B-frags: wave -> (mt2 = wv>>1, nt2 = wv&1); cols o = nt2*16+lr.
  const int nt2 = wv & 1, mt2 = wv >> 1;
  half8 B2[9];
  #pragma unroll
  for (int kt = 0; kt < 9; ++kt)
    B2[kt] = cvt8(c2w + (nt2 * 16 + lr) * 288 + kt * 32 + lg * 8);

  __syncthreads();

  float* img = imgW + wv * 243;
  float* a1  = a1W + wv * 1152;

  for (int ch = 0; ch < 4; ++ch) {        // 4 chunks x 16 samples
    for (int rep = 0; rep < 2; ++rep) {   // 2 samples per wave per chunk
      const int sl = wv * 2 + rep;        // sample-local in chunk
      const int n  = t * 64 + ch * 16 + sl;
      const float* src = inp + n * 147;
      __syncthreads();   // separates prev chunk's GEMM reads from ic2 writes
      // img[c][p+1][q+1] = inp[n][q][p][c]  (verified round-1 transpose)
      for (int i = lane; i < 147; i += 64) {
        int c = i % 3, p = (i / 3) % 7, q = i / 21;
        img[(c * 9 + p + 1) * 9 + q + 1] = src[q * 21 + p * 3 + c];
      }
      __syncthreads();
      // conv1 direct: 512 outs, w from LDS (transposed -> conflict-free)
      for (int r = 0; r < 8; ++r) {
        int idx = r * 64 + lane;
        int o = idx >> 4, s4 = idx & 15, p = s4 >> 2, q = s4 & 3;
        float acc = c1b[o];
        #pragma unroll
        for (int i = 0; i < 3; ++i)
          #pragma unroll
          for (int dp = 0; dp < 3; ++dp)
            #pragma unroll
            for (int dq = 0; dq < 3; ++dq)
              acc += img[(i * 9 + 2 * p + dp) * 9 + 2 * q + dq] *
                     w1t[(i * 9 + dp * 3 + dq) * 32 + o];
        a1[(o * 6 + p + 1) * 6 + q + 1] = eluf(acc);
      }
      __syncthreads();
      // emit im2col rows m = sl*4 + pos (padded row stride 320 keeps the
      // 64-span XOR swizzle bijective WITHIN the row — round-2 bug fix)
      for (int rr = 0; rr < 18; ++rr) {
        int i2 = rr * 64 + lane;              // 4 pos x 288 k
        int k = i2 % 288, pos = i2 / 288;
        int p = pos >> 1, q = pos & 1;
        int i = k / 9, r9 = k % 9, dp = r9 / 3, dq = r9 % 3;
        float v = a1[(i * 6 + 2 * p + dp) * 6 + 2 * q + dq];
        int m = sl * 4 + pos;
        ic2[m * 320 + (k ^ ((m & 7) << 3))] = (_Float16)v;
      }
    }
    __syncthreads();
    // conv2 GEMM for this chunk: M=64 (16s x 4pos), K=288, N=32
    {
      float bb = c2b[nt2 * 16 + lr];
      f32x4 acc; acc[0] = bb; acc[1] = bb; acc[2] = bb; acc[3] = bb;
      const int row = mt2 * 16 + lr;
      #pragma unroll
      for (int kt = 0; kt < 9; ++kt) {
        half8 a = *(const half8*)(ic2 + row * 320 + ((kt * 32 + lg * 8) ^ ((row & 7) << 3)));
        acc = MFMA(a, B2[kt], acc);
      }
      #pragma unroll
      for (int r = 0; r < 4; ++r) {
        int m = mt2 * 16 + lg * 4 + r;            // (s2, pos)
        int s2 = m >> 2, pos = m & 3;
        int arow = ch * 16 + s2;
        int col = (nt2 * 16 + lr) * 4 + pos;      // a2 col = o*4+pos
        a2[arow * 128 + (col ^ ((arow & 7) << 3))] = (_Float16)eluf(acc[r]);
      }
    }
  }
  __syncthreads();

  // conv3 GEMM: M=64, K=128 (i*4+pos), N=128; wave = n-tile
  {
    half8 B3[4];
    #pragma unroll
    for (int kt = 0; kt < 4; ++kt) {
      half8 b;
      #pragma unroll
      for (int e = 0; e < 8; ++e) {
        int k = kt * 32 + lg * 8 + e;
        int i = k >> 2, pos = k & 3;
        int widx = 4 + (pos >> 1) * 3 + (pos & 1);   // taps {4,5,7,8}
        b[e] = (_Float16)c3w[(wv * 16 + lr) * 288 + i * 9 + widx];
      }
      B3[kt] = b;
    }
    float bb = c3b[wv * 16 + lr];
    #pragma unroll
    for (int mt = 0; mt < 4; ++mt) {
      f32x4 acc; acc[0] = bb; acc[1] = bb; acc[2] = bb; acc[3] = bb;
      const int row = mt * 16 + lr;
      #pragma unroll
      for (int kt = 0; kt < 4; ++kt) {
        half8 a = *(const half8*)(a2 + row * 128 + ((kt * 32 + lg * 8) ^ ((row & 7) << 3)));
        acc = MFMA(a, B3[kt], acc);
      }
      #pragma unroll
      for (int r = 0; r < 4; ++r) {
        int m = mt * 16 + lg * 4 + r;
        ft[m * 128 + ((wv * 16 + lr) ^ ((m & 7) << 3))] = (_Float16)eluf(acc[r]);
      }
    }
  }
  __syncthreads();

  // GEMM1: y = ft @ riw^T + rib
  {
    half8 R1[4];
    #pragma unroll
    for (int kt = 0; kt < 4; ++kt)
      R1[kt] = cvt8(riw + (wv * 16 + lr) * 128 + kt * 32 + lg * 8);
    float bb = rib[wv * 16 + lr];
    #pragma unroll
    for (int mt = 0; mt < 4; ++mt) {
      f32x4 acc; acc[0] = bb; acc[1] = bb; acc[2] = bb; acc[3] = bb;
      const int row = mt * 16 + lr;
      #pragma unroll
      for (int kt = 0; kt < 4; ++kt) {
        half8 a = *(const half8*)(ft + row * 128 + ((kt * 32 + lg * 8) ^ ((row & 7) << 3)));
        acc = MFMA(a, R1[kt], acc);
      }
      #pragma unroll
      for (int r = 0; r < 4; ++r) {
        int m = mt * 16 + lg * 4 + r;
        yb[m * 128 + ((wv * 16 + lr) ^ ((m & 7) << 3))] = (_Float16)acc[r];
      }
    }
  }
  __syncthreads();

  // GEMM2: xg = y @ wih^T + (bih + bhh); N=512, wave owns gates ty*128+16wv+lr
  {
    half8 W2f[4][4];   // [kt][ty]
    float bg[4];
    #pragma unroll
    for (int ty = 0; ty < 4; ++ty) {
      int g = ty * 128 + wv * 16 + lr;
      bg[ty] = bih[g] + bhh[g];
      #pragma unroll
      for (int kt = 0; kt < 4; ++kt)
        W2f[kt][ty] = cvt8(wih + g * 128 + kt * 32 + lg * 8);
    }
    #pragma unroll
    for (int mt = 0; mt < 4; ++mt) {
      const int row = mt * 16 + lr;
      half8 a[4];
      #pragma unroll
      for (int kt = 0; kt < 4; ++kt)
        a[kt] = *(const half8*)(yb + row * 128 + ((kt * 32 + lg * 8) ^ ((row & 7) << 3)));
      #pragma unroll
      for (int ty = 0; ty < 4; ++ty) {
        f32x4 acc; acc[0] = bg[ty]; acc[1] = bg[ty]; acc[2] = bg[ty]; acc[3] = bg[ty];
        #pragma unroll
        for (int kt = 0; kt < 4; ++kt) acc = MFMA(a[kt], W2f[kt][ty], acc);
        int g = ty * 128 + wv * 16 + lr;
        *(f32x4*)(xg + (size_t)(t * 512 + g) * 64 + mt * 16 + lg * 4) = acc;
      }
    }
  }
}

// ---------------- windowed LSTM (16 steps, MFMA) + readout ------------------
__global__ __launch_bounds__(512, 2) void k_lstm(
    const float* __restrict__ whh, const float* __restrict__ bih,
    const float* __restrict__ bhh, const float* __restrict__ xg,
    const unsigned char* __restrict__ dun,
    const float* __restrict__ row_, const float* __restrict__ rob,
    float* __restrict__ out)
{
  __shared__ _Float16 H[2][64 * 128];   // 32 KB, XOR-swizzled rows

  const int tid  = threadIdx.x;
  const int lane = tid & 63;
  const int wv   = tid >> 6;
  const int lr   = lane & 15, lg = lane >> 4;
  // XCD-chunked swizzle: XCD x gets t in [32x, 32x+32) -> window overlap shares L2
  const int t = ((blockIdx.x & 7) << 5) + (blockIdx.x >> 3);

  // w_hh B-frags: [kt][ty], gate g = ty*128 + 16wv + lr
  half8 Wf[4][4];
  float b0[4];
  #pragma unroll
  for (int ty = 0; ty < 4; ++ty) {
    int g = ty * 128 + wv * 16 + lr;
    b0[ty] = bih[g] + bhh[g];
    #pragma unroll
    for (int kt = 0; kt < 4; ++kt)
      Wf[kt][ty] = cvt8(whh + g * 128 + kt * 32 + lg * 8);
  }

  for (int i = tid; i < 64 * 128 / 2; i += 512) ((unsigned*)H[0])[i] = 0u;

  float c[4][4];   // [mt][r]: sample m = mt*16 + lg*4 + r, cell 16wv+lr
  #pragma unroll
  for (int mt = 0; mt < 4; ++mt)
    #pragma unroll
    for (int r = 0; r < 4; ++r) c[mt][r] = 0.f;

  for (int st = 0; st < 16; ++st) {
    const int ts = t + st - 15;
    _Float16* Hr = H[st & 1];
    _Float16* Hw = H[(st & 1) ^ 1];
    __syncthreads();
    const bool hasX  = (ts >= 0);
    const bool doRst = (st > 0) && hasX;
    #pragma unroll
    for (int mt = 0; mt < 4; ++mt) {
      const int rowA = mt * 16 + lr;
      half8 a[4];
      #pragma unroll
      for (int kt = 0; kt < 4; ++kt)
        a[kt] = *(const half8*)(Hr + rowA * 128 + ((kt * 32 + lg * 8) ^ ((rowA & 7) << 3)));
      if (doRst && dun[ts * 64 + rowA]) {   // done: zero this sample's h row
        #pragma unroll
        for (int kt = 0; kt < 4; ++kt) a[kt] = zero8();
      }
      f32x4 acc[4];
      if (hasX) {
        #pragma unroll
        for (int ty = 0; ty < 4; ++ty)
          acc[ty] = *(const f32x4*)(xg + (size_t)(ts * 512 + ty * 128 + wv * 16 + lr) * 64
                                       + mt * 16 + lg * 4);
      } else {
        #pragma unroll
        for (int ty = 0; ty < 4; ++ty) {
          acc[ty][0] = b0[ty]; acc[ty][1] = b0[ty]; acc[ty][2] = b0[ty]; acc[ty][3] = b0[ty];
        }
      }
      #pragma unroll
      for (int ty = 0; ty < 4; ++ty)
        #pragma unroll
        for (int kt = 0; kt < 4; ++kt)
          acc[ty] = MFMA(a[kt], Wf[kt][ty], acc[ty]);
      if (doRst) {
        const uchar4 d4 = *(const uchar4*)(dun + ts * 64 + mt * 16 + lg * 4);
        if (d4.x) c[mt][0] = 0.f;
        if (d4.y) c[mt][1] = 0.f;
        if (d4.z) c[mt][2] = 0.f;
        if (d4.w) c[mt][3] = 0.f;
      }
      #pragma unroll
      for (int r = 0; r < 4; ++r) {
        float iv = sigf(acc[0][r]);
        float fv = sigf(acc[1][r]);
        float gv = tanhff(acc[2][r]);
        float ov = sigf(acc[3][r]);
        float cn = fmaf(fv, c[mt][r], iv * gv);
        c[mt][r] = cn;
        float hn = ov * tanhff(cn);
        int m = mt * 16 + lg * 4 + r;
        Hw[m * 128 + ((wv * 16 + lr) ^ ((m & 7) << 3))] = (_Float16)hn;
      }
    }
  }
  __syncthreads();

  // readout: out = h_final @ row_^T + rob  (h_final in H[0] after st=15)
  half8 R[4];
  #pragma unroll
  for (int kt = 0; kt < 4; ++kt)
    R[kt] = cvt8(row_ + (wv * 16 + lr) * 128 + kt * 32 + lg * 8);
  float rb2 = rob[wv * 16 + lr];
  #pragma unroll
  for (int mt = 0; mt < 4; ++mt) {
    const int row = mt * 16 + lr;
    f32x4 acc; acc[0] = rb2; acc[1] = rb2; acc[2] = rb2; acc[3] = rb2;
    #pragma unroll
    for (int kt = 0; kt < 4; ++kt) {
      half8 a = *(const half8*)(H[0] + row * 128 + ((kt * 32 + lg * 8) ^ ((row & 7) << 3)));
      acc = MFMA(a, R[kt], acc);
    }
    #pragma unroll
    for (int r = 0; r < 4; ++r) {
      int m = mt * 16 + lg * 4 + r;
      out[(size_t)(t * 64 + m) * 128 + wv * 16 + lr] = acc[r];
    }
  }
}

extern "C" void kernel_launch(void* const* d_in, const int* in_sizes, int n_in,
                              void* d_out, int out_size, void* d_ws, size_t ws_size,
                              hipStream_t stream) {
  const float* inp = (const float*)d_in[0];
  const void*  don = d_in[1];
  const float* c1w = (const float*)d_in[2];
  const float* c1b = (const float*)d_in[3];
  const float* c2w = (const float*)d_in[4];
  const float* c2b = (const float*)d_in[5];
  const float* c3w = (const float*)d_in[6];
  const float* c3b = (const float*)d_in[7];
  const float* riw = (const float*)d_in[8];
  const float* rib = (const float*)d_in[9];
  const float* wih = (const float*)d_in[10];
  const float* whh = (const float*)d_in[11];
  const float* bih = (const float*)d_in[12];
  const float* bhh = (const float*)d_in[13];
  const float* row_ = (const float*)d_in[14];
  const float* rob = (const float*)d_in[15];

  unsigned char* done_u8 = (unsigned char*)d_ws;
  float* xg = (float*)((char*)d_ws + 16384);    // [256][512][64] f32 = 32 MB

  (void)hipFuncSetAttribute((const void*)k_conv,
                            hipFuncAttributeMaxDynamicSharedMemorySize, 147456);

  k_done<<<1, 256, 0, stream>>>((const unsigned char*)don, done_u8);
  k_conv<<<256, 512, 138208, stream>>>(inp, c1w, c1b, c2w, c2b, c3w, c3b,
                                       riw, rib, wih, bih, bhh, xg);
  k_lstm<<<256, 512, 0, stream>>>(whh, bih, bhh, xg, done_u8, row_, rob,
                                  (float*)d_out);
}